// Round 1
// baseline (8415.816 us; speedup 1.0000x reference)
//
#include <hip/hip_runtime.h>
#include <hip/hip_bf16.h>
#include <stdint.h>

// ---------------------------------------------------------------------------
// GCN: x' = ReLU(GCNConv(x)) -> dropout ; twice.
// GCNConv: out = scatter_add(xW[row]*dinv[row]*dinv[col] -> col) + xW*dinv^2 + b
// deg = indegree(col) + 1 (self loop), dinv = rsqrt(deg)
// Dropout must bit-match JAX threefry. JAX >= 0.4.36: threefry_partitionable=1.
// ---------------------------------------------------------------------------

#define N_NODES 50000
#define N_EDGES 800000
#define IN_C 256
#define HID_C 512
#define OUT_C 256

// 1 => modern JAX (jax_threefry_partitionable=True): per-element counter,
//      bits = w0^w1; split is "foldlike".
// 0 => legacy threefry: paired counters (j, j+half); split via iota(4).
#define JAX_PARTITIONABLE 1

struct U2 { unsigned a, b; };

__host__ __device__ constexpr unsigned rotl32(unsigned x, int d) {
  return (x << d) | (x >> (32 - d));
}

#define TF_ROUND(r) { x0 += x1; x1 = rotl32(x1, (r)); x1 ^= x0; }

__host__ __device__ constexpr U2 threefry2x32(unsigned k0, unsigned k1,
                                              unsigned x0, unsigned x1) {
  unsigned ks2 = k0 ^ k1 ^ 0x1BD11BDAu;
  x0 += k0; x1 += k1;
  TF_ROUND(13) TF_ROUND(15) TF_ROUND(26) TF_ROUND(6)  x0 += k1;  x1 += ks2 + 1u;
  TF_ROUND(17) TF_ROUND(29) TF_ROUND(16) TF_ROUND(24) x0 += ks2; x1 += k0 + 2u;
  TF_ROUND(13) TF_ROUND(15) TF_ROUND(26) TF_ROUND(6)  x0 += k0;  x1 += k1 + 3u;
  TF_ROUND(17) TF_ROUND(29) TF_ROUND(16) TF_ROUND(24) x0 += k1;  x1 += ks2 + 4u;
  TF_ROUND(13) TF_ROUND(15) TF_ROUND(26) TF_ROUND(6)  x0 += ks2; x1 += k0 + 5u;
  return U2{x0, x1};
}

// ---------------------------------------------------------------------------
// degree / dinv
// ---------------------------------------------------------------------------
__global__ void deg_kernel(const int* __restrict__ col, float* __restrict__ deg, int E) {
  int e = blockIdx.x * 256 + threadIdx.x;
  if (e < E) atomicAdd(&deg[col[e]], 1.0f);
}

__global__ void dinv_kernel(float* __restrict__ deg, int N) {
  int n = blockIdx.x * 256 + threadIdx.x;
  if (n < N) deg[n] = rsqrtf(deg[n] + 1.0f);
}

// ---------------------------------------------------------------------------
// fp32 tiled GEMM: C[M,N] = A[M,K] @ B[K,N]. BM=BN=64, BK=32, 256 thr, 4x4/thr.
// ---------------------------------------------------------------------------
#define BM 64
#define BN 64
#define BK 32
#define LDT 68  // padded row stride (floats), 16B-aligned, +4 pad breaks conflicts

__global__ __launch_bounds__(256) void gemm_f32(const float* __restrict__ A,
                                                const float* __restrict__ B,
                                                float* __restrict__ C,
                                                int M, int K, int N) {
  __shared__ __align__(16) float As[BK][LDT];  // As[k][m] (transposed)
  __shared__ __align__(16) float Bs[BK][LDT];  // Bs[k][n]
  const int bm = blockIdx.x * BM;
  const int bn = blockIdx.y * BN;
  const int tid = threadIdx.x;
  const int tx = tid & 15;   // n
  const int ty = tid >> 4;   // m
  float acc[4][4] = {};

  for (int k0 = 0; k0 < K; k0 += BK) {
    // A tile: 64x32. 8 float4/row; thread -> (m = tid/8 + 32*pass, kq = (tid&7)*4)
#pragma unroll
    for (int pass = 0; pass < 2; ++pass) {
      int m = (tid >> 3) + pass * 32;
      int kq = (tid & 7) * 4;
      float4 v = make_float4(0.f, 0.f, 0.f, 0.f);
      int gm = bm + m;
      if (gm < M) v = *(const float4*)(A + (size_t)gm * K + k0 + kq);
      As[kq + 0][m] = v.x; As[kq + 1][m] = v.y;
      As[kq + 2][m] = v.z; As[kq + 3][m] = v.w;
    }
    // B tile: 32x64. 16 float4/row; thread -> (k = tid/16 + 16*pass, nq=(tid&15)*4)
#pragma unroll
    for (int pass = 0; pass < 2; ++pass) {
      int k = (tid >> 4) + pass * 16;
      int nq = (tid & 15) * 4;
      float4 v = *(const float4*)(B + (size_t)(k0 + k) * N + bn + nq);
      Bs[k][nq + 0] = v.x; Bs[k][nq + 1] = v.y;
      Bs[k][nq + 2] = v.z; Bs[k][nq + 3] = v.w;
    }
    __syncthreads();
#pragma unroll
    for (int k = 0; k < BK; ++k) {
      float4 av = *(const float4*)(&As[k][ty * 4]);
      float4 bv = *(const float4*)(&Bs[k][tx * 4]);
      float a[4] = {av.x, av.y, av.z, av.w};
      float b[4] = {bv.x, bv.y, bv.z, bv.w};
#pragma unroll
      for (int i = 0; i < 4; ++i)
#pragma unroll
        for (int j = 0; j < 4; ++j)
          acc[i][j] = fmaf(a[i], b[j], acc[i][j]);
    }
    __syncthreads();
  }

#pragma unroll
  for (int i = 0; i < 4; ++i) {
    int gm = bm + ty * 4 + i;
    if (gm < M) {
      float4 v = make_float4(acc[i][0], acc[i][1], acc[i][2], acc[i][3]);
      *(float4*)(C + (size_t)gm * N + bn + tx * 4) = v;
    }
  }
}

// ---------------------------------------------------------------------------
// scatter: one wave per edge. out[col] += X[row] * dinv[row]*dinv[col]
// ---------------------------------------------------------------------------
template <int F>
__global__ __launch_bounds__(256) void scatter_add(const float* __restrict__ X,
                                                   const int* __restrict__ row,
                                                   const int* __restrict__ col,
                                                   const float* __restrict__ dinv,
                                                   float* __restrict__ out, int E) {
  int wave = (blockIdx.x * 256 + threadIdx.x) >> 6;
  int lane = threadIdx.x & 63;
  if (wave >= E) return;
  int r = row[wave];
  int c = col[wave];
  float norm = dinv[r] * dinv[c];
  const float* src = X + (size_t)r * F;
  float* dst = out + (size_t)c * F;
#pragma unroll
  for (int f0 = lane * 4; f0 < F; f0 += 256) {
    float4 v = *(const float4*)(src + f0);
    atomicAdd(dst + f0 + 0, v.x * norm);
    atomicAdd(dst + f0 + 1, v.y * norm);
    atomicAdd(dst + f0 + 2, v.z * norm);
    atomicAdd(dst + f0 + 3, v.w * norm);
  }
}

// ---------------------------------------------------------------------------
// epilogue (in place on agg): v = agg + xw*dinv^2 + bias; relu; dropout(0.5)
// Each thread handles 2 elements.
// ---------------------------------------------------------------------------
template <int F, int LOGF>
__global__ __launch_bounds__(256) void epilogue(float* __restrict__ agg,
                                                const float* __restrict__ xw,
                                                const float* __restrict__ dinv,
                                                const float* __restrict__ bias,
                                                unsigned kk0, unsigned kk1,
                                                int total) {
  int t = blockIdx.x * 256 + threadIdx.x;
  int half = total >> 1;
  if (t >= half) return;
#if JAX_PARTITIONABLE
  int e0 = 2 * t;
  int e1 = e0 + 1;
  U2 r0 = threefry2x32(kk0, kk1, 0u, (unsigned)e0);
  U2 r1 = threefry2x32(kk0, kk1, 0u, (unsigned)e1);
  unsigned bits0 = r0.a ^ r0.b;
  unsigned bits1 = r1.a ^ r1.b;
#else
  int e0 = t;
  int e1 = t + half;
  U2 rr = threefry2x32(kk0, kk1, (unsigned)e0, (unsigned)e1);
  unsigned bits0 = rr.a;
  unsigned bits1 = rr.b;
#endif
  {
    int node = e0 >> LOGF, feat = e0 & (F - 1);
    float di = dinv[node];
    float v = fmaxf(agg[e0] + xw[e0] * di * di + bias[feat], 0.f);
    agg[e0] = (bits0 >> 31) ? 0.f : v * 2.0f;
  }
  {
    int node = e1 >> LOGF, feat = e1 & (F - 1);
    float di = dinv[node];
    float v = fmaxf(agg[e1] + xw[e1] * di * di + bias[feat], 0.f);
    agg[e1] = (bits1 >> 31) ? 0.f : v * 2.0f;
  }
}

// ---------------------------------------------------------------------------
extern "C" void kernel_launch(void* const* d_in, const int* in_sizes, int n_in,
                              void* d_out, int out_size, void* d_ws, size_t ws_size,
                              hipStream_t stream) {
  const float* x  = (const float*)d_in[0];
  const int*   ei = (const int*)d_in[1];
  const float* W1 = (const float*)d_in[2];
  const float* b1 = (const float*)d_in[3];
  const float* W2 = (const float*)d_in[4];
  const float* b2 = (const float*)d_in[5];
  float* out = (float*)d_out;
  (void)in_sizes; (void)n_in; (void)out_size; (void)ws_size;

  const int* row = ei;            // edge_index[0]
  const int* col = ei + N_EDGES;  // edge_index[1]

  // workspace layout: dinv (256KB slot) | buf1 (102.4MB) | buf2 (102.4MB)
  char* ws = (char*)d_ws;
  float* dinv = (float*)ws;
  float* buf1 = (float*)(ws + (1 << 18));
  float* buf2 = (float*)(ws + (1 << 18) + (size_t)N_NODES * HID_C * 4);

  // dropout keys from jax.random.split(jax.random.key(42)) at compile time
#if JAX_PARTITIONABLE
  constexpr U2 K1 = threefry2x32(0u, 42u, 0u, 0u);
  constexpr U2 K2 = threefry2x32(0u, 42u, 0u, 1u);
#else
  constexpr U2 TA = threefry2x32(0u, 42u, 0u, 2u);
  constexpr U2 TB = threefry2x32(0u, 42u, 1u, 3u);
  constexpr U2 K1 = {TA.a, TB.a};
  constexpr U2 K2 = {TA.b, TB.b};
#endif

  // degree -> dinv
  hipMemsetAsync(dinv, 0, N_NODES * sizeof(float), stream);
  deg_kernel<<<(N_EDGES + 255) / 256, 256, 0, stream>>>(col, dinv, N_EDGES);
  dinv_kernel<<<(N_NODES + 255) / 256, 256, 0, stream>>>(dinv, N_NODES);

  // ---- layer 1 ----
  gemm_f32<<<dim3((N_NODES + BM - 1) / BM, HID_C / BN), 256, 0, stream>>>(
      x, W1, buf1, N_NODES, IN_C, HID_C);
  hipMemsetAsync(buf2, 0, (size_t)N_NODES * HID_C * sizeof(float), stream);
  scatter_add<HID_C><<<(N_EDGES + 3) / 4, 256, 0, stream>>>(
      buf1, row, col, dinv, buf2, N_EDGES);
  epilogue<HID_C, 9><<<(N_NODES * HID_C / 2 + 255) / 256, 256, 0, stream>>>(
      buf2, buf1, dinv, b1, K1.a, K1.b, N_NODES * HID_C);

  // ---- layer 2 ----  (buf2 = h; xW2 -> buf1; agg2 -> d_out)
  gemm_f32<<<dim3((N_NODES + BM - 1) / BM, OUT_C / BN), 256, 0, stream>>>(
      buf2, W2, buf1, N_NODES, HID_C, OUT_C);
  hipMemsetAsync(out, 0, (size_t)N_NODES * OUT_C * sizeof(float), stream);
  scatter_add<OUT_C><<<(N_EDGES + 3) / 4, 256, 0, stream>>>(
      buf1, row, col, dinv, out, N_EDGES);
  epilogue<OUT_C, 8><<<(N_NODES * OUT_C / 2 + 255) / 256, 256, 0, stream>>>(
      out, buf1, dinv, b2, K2.a, K2.b, N_NODES * OUT_C);
}

// Round 2
// 719.106 us; speedup vs baseline: 11.7032x; 11.7032x over previous
//
#include <hip/hip_runtime.h>
#include <hip/hip_bf16.h>
#include <stdint.h>

// ---------------------------------------------------------------------------
// GCN restructured: aggregate (CSR gather, no atomics) then GEMM.
//   agg1 = A_hat x            [50k,256]  gather
//   h    = relu+drop(agg1 W1+b1)         GEMM + fused epilogue
//   hw2  = h W2               [50k,256]  GEMM
//   out  = relu+drop(A_hat hw2 + b2)     gather + fused epilogue
// ---------------------------------------------------------------------------

#define N_NODES 50000
#define N_EDGES 800000
#define IN_C 256
#define HID_C 512
#define OUT_C 256

struct U2 { unsigned a, b; };

__host__ __device__ constexpr unsigned rotl32(unsigned x, int d) {
  return (x << d) | (x >> (32 - d));
}

#define TF_ROUND(r) { x0 += x1; x1 = rotl32(x1, (r)); x1 ^= x0; }

__host__ __device__ constexpr U2 threefry2x32(unsigned k0, unsigned k1,
                                              unsigned x0, unsigned x1) {
  unsigned ks2 = k0 ^ k1 ^ 0x1BD11BDAu;
  x0 += k0; x1 += k1;
  TF_ROUND(13) TF_ROUND(15) TF_ROUND(26) TF_ROUND(6)  x0 += k1;  x1 += ks2 + 1u;
  TF_ROUND(17) TF_ROUND(29) TF_ROUND(16) TF_ROUND(24) x0 += ks2; x1 += k0 + 2u;
  TF_ROUND(13) TF_ROUND(15) TF_ROUND(26) TF_ROUND(6)  x0 += k0;  x1 += k1 + 3u;
  TF_ROUND(17) TF_ROUND(29) TF_ROUND(16) TF_ROUND(24) x0 += k1;  x1 += ks2 + 4u;
  TF_ROUND(13) TF_ROUND(15) TF_ROUND(26) TF_ROUND(6)  x0 += ks2; x1 += k0 + 5u;
  return U2{x0, x1};
}

__device__ inline float drop_apply(float v, unsigned idx, unsigned k0, unsigned k1) {
  v = fmaxf(v, 0.f);
  U2 r = threefry2x32(k0, k1, 0u, idx);
  unsigned bits = r.a ^ r.b;
  return (bits >> 31) ? 0.f : v * 2.0f;
}

// ---------------------------------------------------------------------------
// degree histogram / dinv
// ---------------------------------------------------------------------------
__global__ void deg_kernel(const int* __restrict__ col, int* __restrict__ cnt, int E) {
  int e = blockIdx.x * 256 + threadIdx.x;
  if (e < E) atomicAdd(&cnt[col[e]], 1);
}

__global__ void dinv_kernel(const int* __restrict__ cnt, float* __restrict__ dinv, int N) {
  int n = blockIdx.x * 256 + threadIdx.x;
  if (n < N) dinv[n] = rsqrtf((float)cnt[n] + 1.0f);
}

// ---------------------------------------------------------------------------
// exclusive scan of cnt[0..n) -> indptr, 3-kernel hierarchical (chunk=1024)
// ---------------------------------------------------------------------------
__global__ __launch_bounds__(1024) void scan_local(const int* __restrict__ cnt,
                                                   int* __restrict__ indptr,
                                                   int* __restrict__ chunkSums, int n) {
  __shared__ int s[1024];
  int gid = blockIdx.x * 1024 + threadIdx.x;
  int v = (gid < n) ? cnt[gid] : 0;
  s[threadIdx.x] = v;
  __syncthreads();
#pragma unroll
  for (int off = 1; off < 1024; off <<= 1) {
    int t = (threadIdx.x >= off) ? s[threadIdx.x - off] : 0;
    __syncthreads();
    s[threadIdx.x] += t;
    __syncthreads();
  }
  if (gid < n) indptr[gid] = s[threadIdx.x] - v;  // exclusive
  if (threadIdx.x == 1023) chunkSums[blockIdx.x] = s[1023];
}

__global__ void scan_chunks(int* __restrict__ chunkSums, int nChunks) {
  if (threadIdx.x == 0 && blockIdx.x == 0) {
    int acc = 0;
    for (int i = 0; i < nChunks; ++i) { int t = chunkSums[i]; chunkSums[i] = acc; acc += t; }
  }
}

__global__ void add_offsets(int* __restrict__ indptr, const int* __restrict__ chunkSums,
                            int n, int total) {
  int gid = blockIdx.x * 256 + threadIdx.x;
  if (gid < n) indptr[gid] += chunkSums[gid >> 10];
  if (gid == 0) indptr[n] = total;
}

__global__ void build_csr(const int* __restrict__ row, const int* __restrict__ col,
                          const int* __restrict__ indptr, int* __restrict__ cursor,
                          int* __restrict__ srcSorted, int E) {
  int e = blockIdx.x * 256 + threadIdx.x;
  if (e < E) {
    int c = col[e];
    int p = indptr[c] + atomicAdd(&cursor[c], 1);
    srcSorted[p] = row[e];
  }
}

// ---------------------------------------------------------------------------
// gather-aggregate: one wave per node, F=256 (one float4/lane).
// out[c] = (sum_e x[src_e]*dinv[src_e] + x[c]*dinv[c]) * dinv[c]  [+epilogue]
// ---------------------------------------------------------------------------
template <bool EPI>
__global__ __launch_bounds__(256) void gather_agg(const float* __restrict__ X,
                                                  const int* __restrict__ indptr,
                                                  const int* __restrict__ srcSorted,
                                                  const float* __restrict__ dinv,
                                                  const float* __restrict__ bias,
                                                  float* __restrict__ out,
                                                  unsigned kk0, unsigned kk1, int N) {
  int wid = (blockIdx.x * 256 + threadIdx.x) >> 6;
  int lane = threadIdx.x & 63;
  if (wid >= N) return;
  int beg = __builtin_amdgcn_readfirstlane(indptr[wid]);
  int end = __builtin_amdgcn_readfirstlane(indptr[wid + 1]);
  float dc = dinv[wid];
  const int f0 = lane * 4;
  float4 sv = *(const float4*)(X + (size_t)wid * 256 + f0);
  float a0 = sv.x * dc, a1 = sv.y * dc, a2 = sv.z * dc, a3 = sv.w * dc;
  int e = beg;
  for (; e + 2 <= end; e += 2) {
    int r0 = srcSorted[e], r1 = srcSorted[e + 1];
    float w0 = dinv[r0], w1 = dinv[r1];
    float4 v0 = *(const float4*)(X + (size_t)r0 * 256 + f0);
    float4 v1 = *(const float4*)(X + (size_t)r1 * 256 + f0);
    a0 += v0.x * w0; a1 += v0.y * w0; a2 += v0.z * w0; a3 += v0.w * w0;
    a0 += v1.x * w1; a1 += v1.y * w1; a2 += v1.z * w1; a3 += v1.w * w1;
  }
  if (e < end) {
    int r0 = srcSorted[e];
    float w0 = dinv[r0];
    float4 v0 = *(const float4*)(X + (size_t)r0 * 256 + f0);
    a0 += v0.x * w0; a1 += v0.y * w0; a2 += v0.z * w0; a3 += v0.w * w0;
  }
  a0 *= dc; a1 *= dc; a2 *= dc; a3 *= dc;
  if (EPI) {
    unsigned base = (unsigned)wid * 256u + (unsigned)f0;
    a0 = drop_apply(a0 + bias[f0 + 0], base + 0, kk0, kk1);
    a1 = drop_apply(a1 + bias[f0 + 1], base + 1, kk0, kk1);
    a2 = drop_apply(a2 + bias[f0 + 2], base + 2, kk0, kk1);
    a3 = drop_apply(a3 + bias[f0 + 3], base + 3, kk0, kk1);
  }
  *(float4*)(out + (size_t)wid * 256 + f0) = make_float4(a0, a1, a2, a3);
}

// ---------------------------------------------------------------------------
// fp32 tiled GEMM: C[M,N] = A[M,K] @ B[K,N]  (+ fused bias/relu/dropout)
// BM=BN=64, BK=32, 256 thr, 4x4 micro-tile.
// ---------------------------------------------------------------------------
#define BM 64
#define BN 64
#define BK 32
#define LDT 68

template <bool EPI>
__global__ __launch_bounds__(256) void gemm_f32(const float* __restrict__ A,
                                                const float* __restrict__ B,
                                                float* __restrict__ C,
                                                int M, int K, int N,
                                                const float* __restrict__ bias,
                                                unsigned kk0, unsigned kk1) {
  __shared__ __align__(16) float As[BK][LDT];
  __shared__ __align__(16) float Bs[BK][LDT];
  const int bm = blockIdx.x * BM;
  const int bn = blockIdx.y * BN;
  const int tid = threadIdx.x;
  const int tx = tid & 15;
  const int ty = tid >> 4;
  float acc[4][4] = {};

  for (int k0 = 0; k0 < K; k0 += BK) {
#pragma unroll
    for (int pass = 0; pass < 2; ++pass) {
      int m = (tid >> 3) + pass * 32;
      int kq = (tid & 7) * 4;
      float4 v = make_float4(0.f, 0.f, 0.f, 0.f);
      int gm = bm + m;
      if (gm < M) v = *(const float4*)(A + (size_t)gm * K + k0 + kq);
      As[kq + 0][m] = v.x; As[kq + 1][m] = v.y;
      As[kq + 2][m] = v.z; As[kq + 3][m] = v.w;
    }
#pragma unroll
    for (int pass = 0; pass < 2; ++pass) {
      int k = (tid >> 4) + pass * 16;
      int nq = (tid & 15) * 4;
      float4 v = *(const float4*)(B + (size_t)(k0 + k) * N + bn + nq);
      Bs[k][nq + 0] = v.x; Bs[k][nq + 1] = v.y;
      Bs[k][nq + 2] = v.z; Bs[k][nq + 3] = v.w;
    }
    __syncthreads();
#pragma unroll
    for (int k = 0; k < BK; ++k) {
      float4 av = *(const float4*)(&As[k][ty * 4]);
      float4 bv = *(const float4*)(&Bs[k][tx * 4]);
      float a[4] = {av.x, av.y, av.z, av.w};
      float b[4] = {bv.x, bv.y, bv.z, bv.w};
#pragma unroll
      for (int i = 0; i < 4; ++i)
#pragma unroll
        for (int j = 0; j < 4; ++j)
          acc[i][j] = fmaf(a[i], b[j], acc[i][j]);
    }
    __syncthreads();
  }

#pragma unroll
  for (int i = 0; i < 4; ++i) {
    int gm = bm + ty * 4 + i;
    if (gm < M) {
      int gn = bn + tx * 4;
      float v[4] = {acc[i][0], acc[i][1], acc[i][2], acc[i][3]};
      if (EPI) {
#pragma unroll
        for (int j = 0; j < 4; ++j) {
          unsigned idx = (unsigned)gm * (unsigned)N + (unsigned)(gn + j);
          v[j] = drop_apply(v[j] + bias[gn + j], idx, kk0, kk1);
        }
      }
      *(float4*)(C + (size_t)gm * N + gn) = make_float4(v[0], v[1], v[2], v[3]);
    }
  }
}

// ---------------------------------------------------------------------------
extern "C" void kernel_launch(void* const* d_in, const int* in_sizes, int n_in,
                              void* d_out, int out_size, void* d_ws, size_t ws_size,
                              hipStream_t stream) {
  const float* x  = (const float*)d_in[0];
  const int*   ei = (const int*)d_in[1];
  const float* W1 = (const float*)d_in[2];
  const float* b1 = (const float*)d_in[3];
  const float* W2 = (const float*)d_in[4];
  const float* b2 = (const float*)d_in[5];
  float* out = (float*)d_out;
  (void)in_sizes; (void)n_in; (void)out_size; (void)ws_size;

  const int* row = ei;
  const int* col = ei + N_EDGES;

  // workspace layout
  char* ws = (char*)d_ws;
  float* dinv      = (float*)(ws);                    // 200 KB
  int*   cnt       = (int*)  (ws + (1u << 18));       // 200 KB
  int*   indptr    = (int*)  (ws + (2u << 18));       // 200 KB (+4)
  int*   cursor    = (int*)  (ws + (3u << 18));       // 200 KB
  int*   chunkSums = (int*)  (ws + (4u << 18));       // tiny
  int*   srcSorted = (int*)  (ws + (4u << 18) + (1u << 16));  // 3.2 MB
  float* bufA      = (float*)(ws + (8u << 20));       // 51.2 MB  [50k,256]
  float* bufB      = (float*)(ws + (8u << 20) + 56u * (1u << 20)); // 102.4 MB [50k,512]

  // dropout keys: jax.random.split(jax.random.key(42)), partitionable threefry
  constexpr U2 K1 = threefry2x32(0u, 42u, 0u, 0u);
  constexpr U2 K2 = threefry2x32(0u, 42u, 0u, 1u);

  // ---- degrees + CSR build ----
  hipMemsetAsync(cnt, 0, N_NODES * sizeof(int), stream);
  hipMemsetAsync(cursor, 0, N_NODES * sizeof(int), stream);
  deg_kernel<<<(N_EDGES + 255) / 256, 256, 0, stream>>>(col, cnt, N_EDGES);
  dinv_kernel<<<(N_NODES + 255) / 256, 256, 0, stream>>>(cnt, dinv, N_NODES);
  const int nChunks = (N_NODES + 1023) / 1024;
  scan_local<<<nChunks, 1024, 0, stream>>>(cnt, indptr, chunkSums, N_NODES);
  scan_chunks<<<1, 64, 0, stream>>>(chunkSums, nChunks);
  add_offsets<<<(N_NODES + 255) / 256, 256, 0, stream>>>(indptr, chunkSums, N_NODES, N_EDGES);
  build_csr<<<(N_EDGES + 255) / 256, 256, 0, stream>>>(row, col, indptr, cursor, srcSorted, N_EDGES);

  // ---- layer 1: agg then GEMM(+epi) ----
  gather_agg<false><<<(N_NODES + 3) / 4, 256, 0, stream>>>(
      x, indptr, srcSorted, dinv, nullptr, bufA, 0u, 0u, N_NODES);
  gemm_f32<true><<<dim3((N_NODES + BM - 1) / BM, HID_C / BN), 256, 0, stream>>>(
      bufA, W1, bufB, N_NODES, IN_C, HID_C, b1, K1.a, K1.b);

  // ---- layer 2: GEMM then agg(+epi) ----
  gemm_f32<false><<<dim3((N_NODES + BM - 1) / BM, OUT_C / BN), 256, 0, stream>>>(
      bufB, W2, bufA, N_NODES, HID_C, OUT_C, nullptr, 0u, 0u);
  gather_agg<true><<<(N_NODES + 3) / 4, 256, 0, stream>>>(
      bufA, indptr, srcSorted, dinv, b2, out, K2.a, K2.b, N_NODES);
}

// Round 3
// 369.940 us; speedup vs baseline: 22.7491x; 1.9438x over previous
//
#include <hip/hip_runtime.h>
#include <stdint.h>

// ---------------------------------------------------------------------------
// GCN: agg1 = A_hat x (bf16 gather) ; h = relu+drop(agg1 W1 + b1) (MFMA GEMM)
//      hw2 = h W2 (MFMA GEMM) ; out = relu+drop(A_hat hw2 + b2) (gather)
// ---------------------------------------------------------------------------

#define N_NODES 50000
#define N_EDGES 800000
#define M_PAD   50048   // 391 * 128
#define IN_C 256
#define HID_C 512
#define OUT_C 256

typedef __attribute__((ext_vector_type(8))) short bf16x8;
typedef __attribute__((ext_vector_type(4))) float f32x4;

struct U2 { unsigned a, b; };

__host__ __device__ constexpr unsigned rotl32(unsigned x, int d) {
  return (x << d) | (x >> (32 - d));
}

#define TF_ROUND(r) { x0 += x1; x1 = rotl32(x1, (r)); x1 ^= x0; }

__host__ __device__ constexpr U2 threefry2x32(unsigned k0, unsigned k1,
                                              unsigned x0, unsigned x1) {
  unsigned ks2 = k0 ^ k1 ^ 0x1BD11BDAu;
  x0 += k0; x1 += k1;
  TF_ROUND(13) TF_ROUND(15) TF_ROUND(26) TF_ROUND(6)  x0 += k1;  x1 += ks2 + 1u;
  TF_ROUND(17) TF_ROUND(29) TF_ROUND(16) TF_ROUND(24) x0 += ks2; x1 += k0 + 2u;
  TF_ROUND(13) TF_ROUND(15) TF_ROUND(26) TF_ROUND(6)  x0 += k0;  x1 += k1 + 3u;
  TF_ROUND(17) TF_ROUND(29) TF_ROUND(16) TF_ROUND(24) x0 += k1;  x1 += ks2 + 4u;
  TF_ROUND(13) TF_ROUND(15) TF_ROUND(26) TF_ROUND(6)  x0 += ks2; x1 += k0 + 5u;
  return U2{x0, x1};
}

__device__ __forceinline__ float drop_apply(float v, unsigned idx, unsigned k0, unsigned k1) {
  v = fmaxf(v, 0.f);
  U2 r = threefry2x32(k0, k1, 0u, idx);
  unsigned bits = r.a ^ r.b;
  return (bits >> 31) ? 0.f : v * 2.0f;
}

__device__ __forceinline__ ushort f2b(float f) {  // RTNE
  unsigned u = __builtin_bit_cast(unsigned, f);
  unsigned r = (u + 0x7fffu + ((u >> 16) & 1u)) >> 16;
  return (ushort)r;
}
__device__ __forceinline__ float b2f(ushort h) {
  unsigned u = (unsigned)h << 16;
  return __builtin_bit_cast(float, u);
}

__device__ __forceinline__ void gload16(const void* g, void* l) {
  __builtin_amdgcn_global_load_lds(
      (const __attribute__((address_space(1))) void*)g,
      (__attribute__((address_space(3))) void*)l, 16, 0, 0);
}

// ---------------------------------------------------------------------------
// degree / dinv / scan / CSR build
// ---------------------------------------------------------------------------
__global__ void deg_kernel(const int* __restrict__ col, int* __restrict__ cnt, int E) {
  int e = blockIdx.x * 256 + threadIdx.x;
  if (e < E) atomicAdd(&cnt[col[e]], 1);
}

__global__ void dinv_kernel(const int* __restrict__ cnt, float* __restrict__ dinv, int N) {
  int n = blockIdx.x * 256 + threadIdx.x;
  if (n < N) dinv[n] = rsqrtf((float)cnt[n] + 1.0f);
}

__global__ __launch_bounds__(1024) void scan_local(const int* __restrict__ cnt,
                                                   int* __restrict__ indptr,
                                                   int* __restrict__ chunkSums, int n) {
  __shared__ int s[1024];
  int gid = blockIdx.x * 1024 + threadIdx.x;
  int v = (gid < n) ? cnt[gid] : 0;
  s[threadIdx.x] = v;
  __syncthreads();
#pragma unroll
  for (int off = 1; off < 1024; off <<= 1) {
    int t = (threadIdx.x >= off) ? s[threadIdx.x - off] : 0;
    __syncthreads();
    s[threadIdx.x] += t;
    __syncthreads();
  }
  if (gid < n) indptr[gid] = s[threadIdx.x] - v;
  if (threadIdx.x == 1023) chunkSums[blockIdx.x] = s[1023];
}

__global__ void scan_chunks(int* __restrict__ chunkSums, int nChunks) {
  if (threadIdx.x == 0 && blockIdx.x == 0) {
    int acc = 0;
    for (int i = 0; i < nChunks; ++i) { int t = chunkSums[i]; chunkSums[i] = acc; acc += t; }
  }
}

__global__ void add_offsets(int* __restrict__ indptr, const int* __restrict__ chunkSums,
                            int n, int total) {
  int gid = blockIdx.x * 256 + threadIdx.x;
  if (gid < n) indptr[gid] += chunkSums[gid >> 10];
  if (gid == 0) indptr[n] = total;
}

__global__ void build_csr(const int* __restrict__ row, const int* __restrict__ col,
                          const int* __restrict__ indptr, int* __restrict__ cursor,
                          int* __restrict__ srcSorted, int E) {
  int e = blockIdx.x * 256 + threadIdx.x;
  if (e < E) {
    int c = col[e];
    int p = indptr[c] + atomicAdd(&cursor[c], 1);
    srcSorted[p] = row[e];
  }
}

// ---------------------------------------------------------------------------
// converts
// ---------------------------------------------------------------------------
__global__ void cvt_f32_bf16(const float* __restrict__ in, ushort* __restrict__ out, int n4) {
  int i = blockIdx.x * 256 + threadIdx.x;
  if (i < n4) {
    float4 v = *(const float4*)(in + (size_t)i * 4);
    ushort4 o = make_ushort4(f2b(v.x), f2b(v.y), f2b(v.z), f2b(v.w));
    *(ushort4*)(out + (size_t)i * 4) = o;
  }
}

// WT[n][k] = bf16(W[k][n]);  K = 1<<LOGK
template <int LOGK>
__global__ void wT_kernel(const float* __restrict__ W, ushort* __restrict__ WT, int N, int total) {
  int i = blockIdx.x * 256 + threadIdx.x;
  if (i < total) {
    int k = i & ((1 << LOGK) - 1);
    int n = i >> LOGK;
    WT[i] = f2b(W[(size_t)k * N + n]);
  }
}

// ---------------------------------------------------------------------------
// gather-aggregate over CSR, bf16 table [*,256], one wave per node.
// EPI=false: out bf16 (layer-1 agg). EPI=true: bias/relu/drop, out fp32.
// ---------------------------------------------------------------------------
template <bool EPI>
__global__ __launch_bounds__(256) void gather_agg16(const ushort* __restrict__ X,
                                                    const int* __restrict__ indptr,
                                                    const int* __restrict__ srcS,
                                                    const float* __restrict__ dinv,
                                                    const float* __restrict__ bias,
                                                    void* __restrict__ outp,
                                                    unsigned kk0, unsigned kk1, int N) {
  int wid = (blockIdx.x * 256 + threadIdx.x) >> 6;
  int lane = threadIdx.x & 63;
  if (wid >= N) return;
  int beg = indptr[wid], end = indptr[wid + 1];
  float dc = dinv[wid];
  const int f0 = lane * 4;
  ushort4 sv = *(const ushort4*)(X + (size_t)wid * 256 + f0);
  float a0 = b2f(sv.x) * dc, a1 = b2f(sv.y) * dc,
        a2 = b2f(sv.z) * dc, a3 = b2f(sv.w) * dc;
  int e = beg;
  for (; e + 2 <= end; e += 2) {
    int r0 = srcS[e], r1 = srcS[e + 1];
    float w0 = dinv[r0], w1 = dinv[r1];
    ushort4 v0 = *(const ushort4*)(X + (size_t)r0 * 256 + f0);
    ushort4 v1 = *(const ushort4*)(X + (size_t)r1 * 256 + f0);
    a0 += b2f(v0.x) * w0; a1 += b2f(v0.y) * w0; a2 += b2f(v0.z) * w0; a3 += b2f(v0.w) * w0;
    a0 += b2f(v1.x) * w1; a1 += b2f(v1.y) * w1; a2 += b2f(v1.z) * w1; a3 += b2f(v1.w) * w1;
  }
  if (e < end) {
    int r0 = srcS[e];
    float w0 = dinv[r0];
    ushort4 v0 = *(const ushort4*)(X + (size_t)r0 * 256 + f0);
    a0 += b2f(v0.x) * w0; a1 += b2f(v0.y) * w0; a2 += b2f(v0.z) * w0; a3 += b2f(v0.w) * w0;
  }
  a0 *= dc; a1 *= dc; a2 *= dc; a3 *= dc;
  if (EPI) {
    unsigned base = (unsigned)wid * 256u + (unsigned)f0;
    a0 = drop_apply(a0 + bias[f0 + 0], base + 0, kk0, kk1);
    a1 = drop_apply(a1 + bias[f0 + 1], base + 1, kk0, kk1);
    a2 = drop_apply(a2 + bias[f0 + 2], base + 2, kk0, kk1);
    a3 = drop_apply(a3 + bias[f0 + 3], base + 3, kk0, kk1);
    *(float4*)((float*)outp + (size_t)wid * 256 + f0) = make_float4(a0, a1, a2, a3);
  } else {
    ushort4 o = make_ushort4(f2b(a0), f2b(a1), f2b(a2), f2b(a3));
    *(ushort4*)((ushort*)outp + (size_t)wid * 256 + f0) = o;
  }
}

// ---------------------------------------------------------------------------
// bf16 MFMA GEMM: C[M,N] = A[M,K] @ BT[N,K]^T.  128x128 tile, BK=32, 4 waves.
// M must be multiple of 128 (padded); N,K multiples of 128/32.
// EPI: fused bias+relu+dropout. BF16OUT: store bf16 else fp32.
// ---------------------------------------------------------------------------
template <bool EPI, bool BF16OUT>
__global__ __launch_bounds__(256) void gemm_bf16(const ushort* __restrict__ A,
                                                 const ushort* __restrict__ BT,
                                                 void* __restrict__ C,
                                                 int M, int K, int N,
                                                 const float* __restrict__ bias,
                                                 unsigned kk0, unsigned kk1) {
  __shared__ __align__(16) ushort Asm[128 * 32];
  __shared__ __align__(16) ushort Bsm[128 * 32];
  const int tid = threadIdx.x;
  const int lane = tid & 63;
  const int wv = tid >> 6;
  const int wr = wv >> 1, wc = wv & 1;
  const int bm = blockIdx.x * 128;
  const int bn = blockIdx.y * 128;

  f32x4 acc[4][4] = {};

  const ushort* Afb = Asm + (wr * 64 + (lane & 15)) * 32 + (lane >> 4) * 8;
  const ushort* Bfb = Bsm + (wc * 64 + (lane & 15)) * 32 + (lane >> 4) * 8;

  for (int k0 = 0; k0 < K; k0 += 32) {
#pragma unroll
    for (int r = 0; r < 2; ++r) {
      int ei = r * 256 + tid;
      int trow = ei >> 2;
      int tcol = (ei & 3) * 8;
      gload16(A + (size_t)(bm + trow) * K + (k0 + tcol), (void*)(Asm + ei * 8));
      gload16(BT + (size_t)(bn + trow) * K + (k0 + tcol), (void*)(Bsm + ei * 8));
    }
    __syncthreads();
    bf16x8 af[4], bf[4];
#pragma unroll
    for (int i = 0; i < 4; ++i) af[i] = *(const bf16x8*)(Afb + i * 16 * 32);
#pragma unroll
    for (int i = 0; i < 4; ++i) bf[i] = *(const bf16x8*)(Bfb + i * 16 * 32);
#pragma unroll
    for (int m = 0; m < 4; ++m)
#pragma unroll
      for (int n = 0; n < 4; ++n)
        acc[m][n] = __builtin_amdgcn_mfma_f32_16x16x32_bf16(af[m], bf[n], acc[m][n], 0, 0, 0);
    __syncthreads();
  }

  // C/D layout: col = lane&15, row = (lane>>4)*4 + reg  [guide §3, m89/m91]
  const int rowbase = bm + wr * 64 + ((lane >> 4) << 2);
  const int colbase = bn + wc * 64 + (lane & 15);
#pragma unroll
  for (int m = 0; m < 4; ++m) {
#pragma unroll
    for (int r = 0; r < 4; ++r) {
      int grow = rowbase + m * 16 + r;
#pragma unroll
      for (int n = 0; n < 4; ++n) {
        int gcol = colbase + n * 16;
        float v = acc[m][n][r];
        if (EPI) v = drop_apply(v + bias[gcol], (unsigned)grow * (unsigned)N + (unsigned)gcol, kk0, kk1);
        if (BF16OUT) ((ushort*)C)[(size_t)grow * N + gcol] = f2b(v);
        else         ((float*)C)[(size_t)grow * N + gcol] = v;
      }
    }
  }
}

// ---------------------------------------------------------------------------
extern "C" void kernel_launch(void* const* d_in, const int* in_sizes, int n_in,
                              void* d_out, int out_size, void* d_ws, size_t ws_size,
                              hipStream_t stream) {
  const float* x  = (const float*)d_in[0];
  const int*   ei = (const int*)d_in[1];
  const float* W1 = (const float*)d_in[2];
  const float* b1 = (const float*)d_in[3];
  const float* W2 = (const float*)d_in[4];
  const float* b2 = (const float*)d_in[5];
  float* out = (float*)d_out;
  (void)in_sizes; (void)n_in; (void)out_size; (void)ws_size;

  const int* row = ei;
  const int* col = ei + N_EDGES;

  // workspace layout (bytes)
  char* ws = (char*)d_ws;
  float*  dinv      = (float*) (ws);                       // 200 KB
  int*    cnt       = (int*)   (ws + (1u << 18));          // 200 KB
  int*    indptr    = (int*)   (ws + (2u << 18));          // 200 KB + 4
  int*    cursor    = (int*)   (ws + (3u << 18));          // 200 KB
  int*    chunkSums = (int*)   (ws + (4u << 18));          // tiny
  int*    srcSorted = (int*)   (ws + (4u << 18) + (1u << 16)); // 3.2 MB
  ushort* W1T       = (ushort*)(ws + 5u  * (1u << 20));    // 256 KB [512][256]
  ushort* W2T       = (ushort*)(ws + 6u  * (1u << 20));    // 256 KB [256][512]
  ushort* x16       = (ushort*)(ws + 8u  * (1u << 20));    // 25.6 MB [50000][256]
  ushort* aggB      = (ushort*)(ws + 36u * (1u << 20));    // 25.6 MB [M_PAD][256]
  ushort* h         = (ushort*)(ws + 64u * (1u << 20));    // 51.2 MB [M_PAD][512]
  ushort* hw2       = (ushort*)(ws + 116u* (1u << 20));    // 25.6 MB [M_PAD][256]

  constexpr U2 K1 = threefry2x32(0u, 42u, 0u, 0u);
  constexpr U2 K2 = threefry2x32(0u, 42u, 0u, 1u);

  // ---- CSR build ----
  hipMemsetAsync(cnt, 0, N_NODES * sizeof(int), stream);
  hipMemsetAsync(cursor, 0, N_NODES * sizeof(int), stream);
  deg_kernel<<<(N_EDGES + 255) / 256, 256, 0, stream>>>(col, cnt, N_EDGES);
  dinv_kernel<<<(N_NODES + 255) / 256, 256, 0, stream>>>(cnt, dinv, N_NODES);
  const int nChunks = (N_NODES + 1023) / 1024;
  scan_local<<<nChunks, 1024, 0, stream>>>(cnt, indptr, chunkSums, N_NODES);
  scan_chunks<<<1, 64, 0, stream>>>(chunkSums, nChunks);
  add_offsets<<<(N_NODES + 255) / 256, 256, 0, stream>>>(indptr, chunkSums, N_NODES, N_EDGES);
  build_csr<<<(N_EDGES + 255) / 256, 256, 0, stream>>>(row, col, indptr, cursor, srcSorted, N_EDGES);

  // ---- converts ----
  cvt_f32_bf16<<<(N_NODES * IN_C / 4 + 255) / 256, 256, 0, stream>>>(x, x16, N_NODES * IN_C / 4);
  wT_kernel<8><<<(IN_C * HID_C + 255) / 256, 256, 0, stream>>>(W1, W1T, HID_C, IN_C * HID_C);
  wT_kernel<9><<<(HID_C * OUT_C + 255) / 256, 256, 0, stream>>>(W2, W2T, OUT_C, HID_C * OUT_C);
  // zero pad rows of aggB (rows 50000..50047)
  hipMemsetAsync(aggB + (size_t)N_NODES * IN_C, 0, (size_t)(M_PAD - N_NODES) * IN_C * 2, stream);

  // ---- layer 1 ----
  gather_agg16<false><<<(N_NODES + 3) / 4, 256, 0, stream>>>(
      x16, indptr, srcSorted, dinv, nullptr, aggB, 0u, 0u, N_NODES);
  gemm_bf16<true, true><<<dim3(M_PAD / 128, HID_C / 128), 256, 0, stream>>>(
      aggB, W1T, h, M_PAD, IN_C, HID_C, b1, K1.a, K1.b);

  // ---- layer 2 ----
  gemm_bf16<false, true><<<dim3(M_PAD / 128, OUT_C / 128), 256, 0, stream>>>(
      h, W2T, hw2, M_PAD, HID_C, OUT_C, nullptr, 0u, 0u);
  gather_agg16<true><<<(N_NODES + 3) / 4, 256, 0, stream>>>(
      hw2, indptr, srcSorted, dinv, b2, out, K2.a, K2.b, N_NODES);
}

// Round 4
// 347.434 us; speedup vs baseline: 24.2228x; 1.0648x over previous
//
#include <hip/hip_runtime.h>
#include <stdint.h>

// ---------------------------------------------------------------------------
// GCN: agg1 = A_hat x (bf16 gather, + layer1 dropout-mask gen)
//      h    = relu+drop(agg1 W1 + b1)   (MFMA GEMM, mask from bitmask)
//      hw2  = h W2                      (MFMA GEMM)
//      out  = relu+drop(A_hat hw2 + b2) (gather + inline threefry epilogue)
// ---------------------------------------------------------------------------

#define N_NODES 50000
#define N_EDGES 800000
#define M_PAD   50048   // 391 * 128
#define IN_C 256
#define HID_C 512
#define OUT_C 256

typedef __attribute__((ext_vector_type(8))) short bf16x8;
typedef __attribute__((ext_vector_type(4))) float f32x4;

struct U2 { unsigned a, b; };

__host__ __device__ constexpr unsigned rotl32(unsigned x, int d) {
  return (x << d) | (x >> (32 - d));
}

#define TF_ROUND(r) { x0 += x1; x1 = rotl32(x1, (r)); x1 ^= x0; }

__host__ __device__ constexpr U2 threefry2x32(unsigned k0, unsigned k1,
                                              unsigned x0, unsigned x1) {
  unsigned ks2 = k0 ^ k1 ^ 0x1BD11BDAu;
  x0 += k0; x1 += k1;
  TF_ROUND(13) TF_ROUND(15) TF_ROUND(26) TF_ROUND(6)  x0 += k1;  x1 += ks2 + 1u;
  TF_ROUND(17) TF_ROUND(29) TF_ROUND(16) TF_ROUND(24) x0 += ks2; x1 += k0 + 2u;
  TF_ROUND(13) TF_ROUND(15) TF_ROUND(26) TF_ROUND(6)  x0 += k0;  x1 += k1 + 3u;
  TF_ROUND(17) TF_ROUND(29) TF_ROUND(16) TF_ROUND(24) x0 += k1;  x1 += ks2 + 4u;
  TF_ROUND(13) TF_ROUND(15) TF_ROUND(26) TF_ROUND(6)  x0 += ks2; x1 += k0 + 5u;
  return U2{x0, x1};
}

__device__ __forceinline__ float drop_apply(float v, unsigned idx, unsigned k0, unsigned k1) {
  v = fmaxf(v, 0.f);
  U2 r = threefry2x32(k0, k1, 0u, idx);
  unsigned bits = r.a ^ r.b;
  return (bits >> 31) ? 0.f : v * 2.0f;
}

__device__ __forceinline__ ushort f2b(float f) {  // RTNE
  unsigned u = __builtin_bit_cast(unsigned, f);
  unsigned r = (u + 0x7fffu + ((u >> 16) & 1u)) >> 16;
  return (ushort)r;
}
__device__ __forceinline__ float b2f(ushort h) {
  unsigned u = (unsigned)h << 16;
  return __builtin_bit_cast(float, u);
}

__device__ __forceinline__ void gload16(const void* g, void* l) {
  __builtin_amdgcn_global_load_lds(
      (const __attribute__((address_space(1))) void*)g,
      (__attribute__((address_space(3))) void*)l, 16, 0, 0);
}

// ---------------------------------------------------------------------------
// degree / dinv / scan / CSR build
// ---------------------------------------------------------------------------
__global__ void deg_kernel(const int* __restrict__ col, int* __restrict__ cnt, int E) {
  int e = blockIdx.x * 256 + threadIdx.x;
  if (e < E) atomicAdd(&cnt[col[e]], 1);
}

__global__ void dinv_kernel(const int* __restrict__ cnt, float* __restrict__ dinv, int N) {
  int n = blockIdx.x * 256 + threadIdx.x;
  if (n < N) dinv[n] = rsqrtf((float)cnt[n] + 1.0f);
}

__global__ __launch_bounds__(1024) void scan_local(const int* __restrict__ cnt,
                                                   int* __restrict__ indptr,
                                                   int* __restrict__ chunkSums, int n) {
  __shared__ int s[1024];
  int gid = blockIdx.x * 1024 + threadIdx.x;
  int v = (gid < n) ? cnt[gid] : 0;
  s[threadIdx.x] = v;
  __syncthreads();
#pragma unroll
  for (int off = 1; off < 1024; off <<= 1) {
    int t = (threadIdx.x >= off) ? s[threadIdx.x - off] : 0;
    __syncthreads();
    s[threadIdx.x] += t;
    __syncthreads();
  }
  if (gid < n) indptr[gid] = s[threadIdx.x] - v;
  if (threadIdx.x == 1023) chunkSums[blockIdx.x] = s[1023];
}

__global__ void scan_chunks(int* __restrict__ chunkSums, int nChunks) {
  if (threadIdx.x == 0 && blockIdx.x == 0) {
    int acc = 0;
    for (int i = 0; i < nChunks; ++i) { int t = chunkSums[i]; chunkSums[i] = acc; acc += t; }
  }
}

__global__ void add_offsets(int* __restrict__ indptr, const int* __restrict__ chunkSums,
                            int n, int total) {
  int gid = blockIdx.x * 256 + threadIdx.x;
  if (gid < n) indptr[gid] += chunkSums[gid >> 10];
  if (gid == 0) indptr[n] = total;
}

__global__ void build_csr(const int* __restrict__ row, const int* __restrict__ col,
                          const int* __restrict__ indptr, int* __restrict__ cursor,
                          int* __restrict__ srcSorted, int E) {
  int e = blockIdx.x * 256 + threadIdx.x;
  if (e < E) {
    int c = col[e];
    int p = indptr[c] + atomicAdd(&cursor[c], 1);
    srcSorted[p] = row[e];
  }
}

// ---------------------------------------------------------------------------
// converts
// ---------------------------------------------------------------------------
__global__ void cvt_f32_bf16(const float* __restrict__ in, ushort* __restrict__ out, int n4) {
  int i = blockIdx.x * 256 + threadIdx.x;
  if (i < n4) {
    float4 v = *(const float4*)(in + (size_t)i * 4);
    ushort4 o = make_ushort4(f2b(v.x), f2b(v.y), f2b(v.z), f2b(v.w));
    *(ushort4*)(out + (size_t)i * 4) = o;
  }
}

template <int LOGK>
__global__ void wT_kernel(const float* __restrict__ W, ushort* __restrict__ WT, int N, int total) {
  int i = blockIdx.x * 256 + threadIdx.x;
  if (i < total) {
    int k = i & ((1 << LOGK) - 1);
    int n = i >> LOGK;
    WT[i] = f2b(W[(size_t)k * N + n]);
  }
}

// ---------------------------------------------------------------------------
// gather-aggregate over CSR, bf16 table [*,256], one wave per node.
// EPI=false: out bf16; also generates layer-1 dropout bitmask (8 bits/lane).
// EPI=true: bias/relu/inline-threefry-drop, out fp32.
// ---------------------------------------------------------------------------
template <bool EPI>
__global__ __launch_bounds__(256) void gather_agg16(const ushort* __restrict__ X,
                                                    const int* __restrict__ indptr,
                                                    const int* __restrict__ srcS,
                                                    const float* __restrict__ dinv,
                                                    const float* __restrict__ bias,
                                                    void* __restrict__ outp,
                                                    unsigned char* __restrict__ maskOut,
                                                    unsigned kk0, unsigned kk1, int N) {
  int wid = (blockIdx.x * 256 + threadIdx.x) >> 6;
  int lane = threadIdx.x & 63;
  if (wid >= N) return;
  int beg = __builtin_amdgcn_readfirstlane(indptr[wid]);
  int end = __builtin_amdgcn_readfirstlane(indptr[wid + 1]);
  float dc = dinv[wid];
  const int f0 = lane * 4;
  ushort4 sv = *(const ushort4*)(X + (size_t)wid * 256 + f0);
  float a0 = b2f(sv.x) * dc, a1 = b2f(sv.y) * dc,
        a2 = b2f(sv.z) * dc, a3 = b2f(sv.w) * dc;
  int e = beg;
  for (; e + 2 <= end; e += 2) {
    int r0 = srcS[e], r1 = srcS[e + 1];
    float w0 = dinv[r0], w1 = dinv[r1];
    ushort4 v0 = *(const ushort4*)(X + (size_t)r0 * 256 + f0);
    ushort4 v1 = *(const ushort4*)(X + (size_t)r1 * 256 + f0);
    a0 += b2f(v0.x) * w0; a1 += b2f(v0.y) * w0; a2 += b2f(v0.z) * w0; a3 += b2f(v0.w) * w0;
    a0 += b2f(v1.x) * w1; a1 += b2f(v1.y) * w1; a2 += b2f(v1.z) * w1; a3 += b2f(v1.w) * w1;
  }
  if (e < end) {
    int r0 = srcS[e];
    float w0 = dinv[r0];
    ushort4 v0 = *(const ushort4*)(X + (size_t)r0 * 256 + f0);
    a0 += b2f(v0.x) * w0; a1 += b2f(v0.y) * w0; a2 += b2f(v0.z) * w0; a3 += b2f(v0.w) * w0;
  }
  a0 *= dc; a1 *= dc; a2 *= dc; a3 *= dc;
  if (EPI) {
    unsigned base = (unsigned)wid * 256u + (unsigned)f0;
    a0 = drop_apply(a0 + bias[f0 + 0], base + 0, kk0, kk1);
    a1 = drop_apply(a1 + bias[f0 + 1], base + 1, kk0, kk1);
    a2 = drop_apply(a2 + bias[f0 + 2], base + 2, kk0, kk1);
    a3 = drop_apply(a3 + bias[f0 + 3], base + 3, kk0, kk1);
    *(float4*)((float*)outp + (size_t)wid * 256 + f0) = make_float4(a0, a1, a2, a3);
  } else {
    ushort4 o = make_ushort4(f2b(a0), f2b(a1), f2b(a2), f2b(a3));
    *(ushort4*)((ushort*)outp + (size_t)wid * 256 + f0) = o;
    // layer-1 dropout mask: this lane packs bits for h elements [gl*8, gl*8+8)
    unsigned gl = (unsigned)wid * 64u + (unsigned)lane;
    unsigned eb = gl * 8u;
    unsigned byte = 0;
#pragma unroll
    for (int j = 0; j < 8; ++j) {
      U2 r = threefry2x32(kk0, kk1, 0u, eb + (unsigned)j);
      byte |= (((r.a ^ r.b) >> 31) & 1u) << j;
    }
    maskOut[gl] = (unsigned char)byte;
  }
}

// ---------------------------------------------------------------------------
// bf16 MFMA GEMM: C[M,N] = A[M,K] @ BT[N,K]^T.  128x128 tile, BK=64, 4 waves,
// double-buffered LDS with prefetch, XOR-swizzled (16B granule, row&7),
// coalesced bf16 C-store via LDS transpose. EPI: bias+relu+bitmask dropout.
// M multiple of 128; K,N multiples of 64/128.
// ---------------------------------------------------------------------------
template <bool EPI>
__global__ __launch_bounds__(256) void gemm_bf16(const ushort* __restrict__ A,
                                                 const ushort* __restrict__ BT,
                                                 ushort* __restrict__ C,
                                                 int M, int K, int N,
                                                 const float* __restrict__ bias,
                                                 const unsigned char* __restrict__ mask) {
  __shared__ __align__(16) ushort lds[4 * 128 * 64];  // A0 A1 B0 B1 (16KB each)
  const int tid = threadIdx.x;
  const int lane = tid & 63;
  const int wv = tid >> 6;
  const int wr = wv >> 1, wc = wv & 1;
  const int bm = blockIdx.x * 128;
  const int bn = blockIdx.y * 128;

  f32x4 acc[4][4] = {};
  const int xorv = (lane & 7) << 4;  // byte-level frag-read swizzle

  auto stage = [&](int buf, int k0) {
#pragma unroll
    for (int l = 0; l < 4; ++l) {
      int cid = l * 256 + tid;
      int row = cid >> 3;
      int kcol = ((cid & 7) ^ (row & 7)) * 8;  // pre-swizzled global source
      gload16(A + (size_t)(bm + row) * K + k0 + kcol, (void*)(lds + buf * 8192 + cid * 8));
      gload16(BT + (size_t)(bn + row) * K + k0 + kcol, (void*)(lds + (2 + buf) * 8192 + cid * 8));
    }
  };

  const int nt = K >> 6;
  stage(0, 0);
  __syncthreads();  // drains vmcnt before barrier (compiler-inserted)
  int cur = 0;
  for (int t = 0; t < nt; ++t) {
    if (t + 1 < nt) stage(cur ^ 1, (t + 1) << 6);
    const char* Ab = (const char*)(lds + cur * 8192);
    const char* Bb = (const char*)(lds + (2 + cur) * 8192);
#pragma unroll
    for (int ks = 0; ks < 2; ++ks) {
      bf16x8 af[4], bf[4];
      const int kb = (ks * 64 + (lane >> 4) * 16) ^ xorv;
#pragma unroll
      for (int i = 0; i < 4; ++i) {
        int arow = wr * 64 + i * 16 + (lane & 15);
        af[i] = *(const bf16x8*)(Ab + arow * 128 + kb);
        int brow = wc * 64 + i * 16 + (lane & 15);
        bf[i] = *(const bf16x8*)(Bb + brow * 128 + kb);
      }
#pragma unroll
      for (int m = 0; m < 4; ++m)
#pragma unroll
        for (int n = 0; n < 4; ++n)
          acc[m][n] = __builtin_amdgcn_mfma_f32_16x16x32_bf16(af[m], bf[n], acc[m][n], 0, 0, 0);
    }
    __syncthreads();  // drains vmcnt(0): prefetched tile ready for next iter
    cur ^= 1;
  }

  // ---- epilogue: acc -> (bias/relu/drop) -> bf16 -> LDS [128][132] -> store
  ushort* Csm = (ushort*)lds;
  const int rowoff = wr * 64 + ((lane >> 4) << 2);
  const int coloff = wc * 64 + (lane & 15);
  float bias_v[4];
  if (EPI) {
#pragma unroll
    for (int n = 0; n < 4; ++n) bias_v[n] = bias[bn + coloff + n * 16];
  }
#pragma unroll
  for (int m = 0; m < 4; ++m) {
#pragma unroll
    for (int r = 0; r < 4; ++r) {
      int lrow = rowoff + m * 16 + r;
      unsigned long long mk = 0;
      if (EPI) {
        unsigned base = (unsigned)(bm + lrow) * (unsigned)N + (unsigned)(bn + wc * 64);
        mk = *(const unsigned long long*)(mask + (base >> 3));
      }
#pragma unroll
      for (int n = 0; n < 4; ++n) {
        float v = acc[m][n][r];
        if (EPI) {
          v = fmaxf(v + bias_v[n], 0.f);
          v = ((mk >> ((lane & 15) + n * 16)) & 1ull) ? 0.f : v * 2.0f;
        }
        Csm[lrow * 132 + coloff + n * 16] = f2b(v);
      }
    }
  }
  __syncthreads();
  {
    int row = tid >> 1, ch = (tid & 1) * 64;
    const ushort* src = Csm + row * 132 + ch;
    ushort* dst = C + (size_t)(bm + row) * N + bn + ch;
#pragma unroll
    for (int j = 0; j < 8; ++j)
      *(bf16x8*)(dst + j * 8) = *(const bf16x8*)(src + j * 8);
  }
}

// ---------------------------------------------------------------------------
extern "C" void kernel_launch(void* const* d_in, const int* in_sizes, int n_in,
                              void* d_out, int out_size, void* d_ws, size_t ws_size,
                              hipStream_t stream) {
  const float* x  = (const float*)d_in[0];
  const int*   ei = (const int*)d_in[1];
  const float* W1 = (const float*)d_in[2];
  const float* b1 = (const float*)d_in[3];
  const float* W2 = (const float*)d_in[4];
  const float* b2 = (const float*)d_in[5];
  float* out = (float*)d_out;
  (void)in_sizes; (void)n_in; (void)out_size; (void)ws_size;

  const int* row = ei;
  const int* col = ei + N_EDGES;

  // workspace layout (bytes)
  char* ws = (char*)d_ws;
  float*  dinv      = (float*) (ws);                         // 200 KB
  int*    cnt       = (int*)   (ws + (1u << 18));            // 200 KB
  int*    indptr    = (int*)   (ws + (2u << 18));            // 200 KB + 4
  int*    cursor    = (int*)   (ws + (3u << 18));            // 200 KB
  int*    chunkSums = (int*)   (ws + (1u << 20));            // tiny
  int*    srcSorted = (int*)   (ws + (1u << 20) + (1u << 16)); // 3.2 MB
  ushort* W1T       = (ushort*)(ws + 5u  * (1u << 20));      // 256 KB [512][256]
  ushort* W2T       = (ushort*)(ws + 5u  * (1u << 20) + (1u << 19)); // 256 KB [256][512]
  unsigned char* mask1 = (unsigned char*)(ws + 6u * (1u << 20)); // 3.21 MB
  ushort* x16       = (ushort*)(ws + 10u * (1u << 20));      // 25.6 MB [50000][256]
  ushort* aggB      = (ushort*)(ws + 36u * (1u << 20));      // 25.6 MB [M_PAD][256]
  ushort* h         = (ushort*)(ws + 64u * (1u << 20));      // 51.2 MB [M_PAD][512]
  ushort* hw2       = (ushort*)(ws + 116u* (1u << 20));      // 25.6 MB [M_PAD][256]

  constexpr U2 K1 = threefry2x32(0u, 42u, 0u, 0u);
  constexpr U2 K2 = threefry2x32(0u, 42u, 0u, 1u);

  // ---- CSR build ----
  hipMemsetAsync(cnt, 0, N_NODES * sizeof(int), stream);
  hipMemsetAsync(cursor, 0, N_NODES * sizeof(int), stream);
  deg_kernel<<<(N_EDGES + 255) / 256, 256, 0, stream>>>(col, cnt, N_EDGES);
  dinv_kernel<<<(N_NODES + 255) / 256, 256, 0, stream>>>(cnt, dinv, N_NODES);
  const int nChunks = (N_NODES + 1023) / 1024;
  scan_local<<<nChunks, 1024, 0, stream>>>(cnt, indptr, chunkSums, N_NODES);
  scan_chunks<<<1, 64, 0, stream>>>(chunkSums, nChunks);
  add_offsets<<<(N_NODES + 255) / 256, 256, 0, stream>>>(indptr, chunkSums, N_NODES, N_EDGES);
  build_csr<<<(N_EDGES + 255) / 256, 256, 0, stream>>>(row, col, indptr, cursor, srcSorted, N_EDGES);

  // ---- converts ----
  cvt_f32_bf16<<<(N_NODES * IN_C / 4 + 255) / 256, 256, 0, stream>>>(x, x16, N_NODES * IN_C / 4);
  wT_kernel<8><<<(IN_C * HID_C + 255) / 256, 256, 0, stream>>>(W1, W1T, HID_C, IN_C * HID_C);
  wT_kernel<9><<<(HID_C * OUT_C + 255) / 256, 256, 0, stream>>>(W2, W2T, OUT_C, HID_C * OUT_C);
  hipMemsetAsync(aggB + (size_t)N_NODES * IN_C, 0, (size_t)(M_PAD - N_NODES) * IN_C * 2, stream);

  // ---- layer 1 ----
  gather_agg16<false><<<(N_NODES + 3) / 4, 256, 0, stream>>>(
      x16, indptr, srcSorted, dinv, nullptr, aggB, mask1, K1.a, K1.b, N_NODES);
  gemm_bf16<true><<<dim3(M_PAD / 128, HID_C / 128), 256, 0, stream>>>(
      aggB, W1T, h, M_PAD, IN_C, HID_C, b1, mask1);

  // ---- layer 2 ----
  gemm_bf16<false><<<dim3(M_PAD / 128, OUT_C / 128), 256, 0, stream>>>(
      h, W2T, hw2, M_PAD, HID_C, OUT_C, nullptr, nullptr);
  gather_agg16<true><<<(N_NODES + 3) / 4, 256, 0, stream>>>(
      hw2, indptr, srcSorted, dinv, b2, out, nullptr, K2.a, K2.b, N_NODES);
}